// Round 1
// baseline (3147.106 us; speedup 1.0000x reference)
//
#include <hip/hip_runtime.h>

#define DIM 128

// out[n][j] = relu(b[j] + sum_k in[n][k] * W[j][k])   (+ xres[n][j] if RESID)
// W staged in LDS (64KB) with XOR chunk-swizzle: element (j,k) lives at
// float index j*128 + (k ^ ((j&7)<<2)).  Read pattern: 128 lanes read 128
// different rows at the same k-chunk -> swizzle spreads them across all banks.
// x rows are read as wave-uniform float4 broadcasts (L1-served).
template<bool RESID>
__global__ __launch_bounds__(256, 2)
void linear_relu_kernel(const float* __restrict__ in, const float* __restrict__ W,
                        const float* __restrict__ b, const float* __restrict__ xres,
                        float* __restrict__ out, int n_nodes, int n_tiles)
{
    __shared__ float Wl[128 * 128];

    const int t = threadIdx.x;
    // cooperative load + swizzle of W: 4096 float4 chunks
    for (int idx = t; idx < (128 * 128) / 4; idx += 256) {
        float4 w = ((const float4*)W)[idx];
        const int j = idx >> 5;              // row
        const int k = (idx & 31) << 2;       // col (multiple of 4)
        const int ks = k ^ ((j & 7) << 2);   // swizzled col
        *((float4*)&Wl[j * 128 + ks]) = w;
    }
    __syncthreads();

    const int j = t & 127;   // output column owned by this thread
    const int h = t >> 7;    // node half-group (0 or 1) -> wave-uniform
    const float bj = b[j];
    const int swz = (j & 7) << 2;

    for (int tile = blockIdx.x; tile < n_tiles; tile += gridDim.x) {
        const int n0 = tile * 8 + h * 4;     // this thread's 4 node rows
        // clamp pointers for (impossible here, but safe) tail tiles
        const int m0 = n0 + 0 < n_nodes ? n0 + 0 : n_nodes - 1;
        const int m1 = n0 + 1 < n_nodes ? n0 + 1 : n_nodes - 1;
        const int m2 = n0 + 2 < n_nodes ? n0 + 2 : n_nodes - 1;
        const int m3 = n0 + 3 < n_nodes ? n0 + 3 : n_nodes - 1;
        const float4* x0 = (const float4*)(in + (size_t)m0 * DIM);
        const float4* x1 = (const float4*)(in + (size_t)m1 * DIM);
        const float4* x2 = (const float4*)(in + (size_t)m2 * DIM);
        const float4* x3 = (const float4*)(in + (size_t)m3 * DIM);

        float acc0 = bj, acc1 = bj, acc2 = bj, acc3 = bj;

        #pragma unroll 8
        for (int kc = 0; kc < 32; ++kc) {
            const float4 w = *((const float4*)&Wl[j * 128 + ((kc << 2) ^ swz)]);
            const float4 a = x0[kc];
            const float4 c = x1[kc];
            const float4 d = x2[kc];
            const float4 e = x3[kc];
            acc0 += w.x * a.x + w.y * a.y + w.z * a.z + w.w * a.w;
            acc1 += w.x * c.x + w.y * c.y + w.z * c.z + w.w * c.w;
            acc2 += w.x * d.x + w.y * d.y + w.z * d.z + w.w * d.w;
            acc3 += w.x * e.x + w.y * e.y + w.z * e.z + w.w * e.w;
        }

        float r0 = fmaxf(acc0, 0.f);
        float r1 = fmaxf(acc1, 0.f);
        float r2 = fmaxf(acc2, 0.f);
        float r3 = fmaxf(acc3, 0.f);
        if (RESID) {
            r0 += xres[(size_t)m0 * DIM + j];
            r1 += xres[(size_t)m1 * DIM + j];
            r2 += xres[(size_t)m2 * DIM + j];
            r3 += xres[(size_t)m3 * DIM + j];
        }
        if (n0 + 0 < n_nodes) out[(size_t)m0 * DIM + j] = r0;
        if (n0 + 1 < n_nodes) out[(size_t)m1 * DIM + j] = r1;
        if (n0 + 2 < n_nodes) out[(size_t)m2 * DIM + j] = r2;
        if (n0 + 3 < n_nodes) out[(size_t)m3 * DIM + j] = r3;
    }
}

// one edge per 32 threads; each thread moves one float4 (16B) of the message
// row and does 4 native fp32 atomic adds into agg[dst].
__global__ __launch_bounds__(256)
void scatter_kernel(const float* __restrict__ msg, const int* __restrict__ ei,
                    float* __restrict__ agg, int n_edges)
{
    const long gid = (long)blockIdx.x * 256 + threadIdx.x;
    const int e = (int)(gid >> 5);
    if (e >= n_edges) return;
    const int l = (int)(gid & 31);

    const int src = ei[e];
    const int dst = ei[n_edges + e];

    const float4 m = ((const float4*)(msg + (size_t)src * DIM))[l];
    float* a = agg + (size_t)dst * DIM + (l << 2);
    unsafeAtomicAdd(a + 0, m.x);
    unsafeAtomicAdd(a + 1, m.y);
    unsafeAtomicAdd(a + 2, m.z);
    unsafeAtomicAdd(a + 3, m.w);
}

extern "C" void kernel_launch(void* const* d_in, const int* in_sizes, int n_in,
                              void* d_out, int out_size, void* d_ws, size_t ws_size,
                              hipStream_t stream)
{
    const float* x  = (const float*)d_in[0];
    const int*   ei = (const int*)d_in[1];
    const float* Wm = (const float*)d_in[2];
    const float* bm = (const float*)d_in[3];
    const float* Wu = (const float*)d_in[4];
    const float* bu = (const float*)d_in[5];

    const int N = in_sizes[0] / DIM;       // 100000
    const int E = in_sizes[1] / 2;         // 1600000

    float* out = (float*)d_out;
    float* msg = out;                      // temp: messages live in d_out
    float* agg = (float*)d_ws;             // scratch: aggregated (N*DIM f32)

    const int n_tiles = (N + 7) / 8;

    // 1) messages = relu(x @ Wm^T + bm)  -> d_out (temp)
    linear_relu_kernel<false><<<512, 256, 0, stream>>>(x, Wm, bm, nullptr, msg, N, n_tiles);

    // 2) agg = 0
    hipMemsetAsync(agg, 0, (size_t)N * DIM * sizeof(float), stream);

    // 3) agg[dst] += msg[src]
    const long n_thr = (long)E * 32;
    scatter_kernel<<<(int)((n_thr + 255) / 256), 256, 0, stream>>>(msg, ei, agg, E);

    // 4) out = relu(agg @ Wu^T + bu) + x  -> d_out (final)
    linear_relu_kernel<true><<<512, 256, 0, stream>>>(agg, Wu, bu, x, out, N, n_tiles);
}

// Round 2
// 765.483 us; speedup vs baseline: 4.1113x; 4.1113x over previous
//
#include <hip/hip_runtime.h>
#include <hip/hip_bf16.h>

#define DIM 128

// out[n][j] = relu(b[j] + sum_k in[n][k] * W[j][k])   (+ xres[n][j] if RESID)
// W staged in LDS with XOR chunk-swizzle (bank-conflict-free column reads).
// RESID instantiation runs IN-PLACE (in == out): rows are partitioned by tile
// -> only the owning block touches a row; __syncthreads() separates the last
// read from the first write. BF16OUT stores bf16 (for the message buffer).
template<bool RESID, bool BF16OUT>
__global__ __launch_bounds__(256, 2)
void linear_relu_kernel(const float* in, const float* __restrict__ W,
                        const float* __restrict__ b, const float* __restrict__ xres,
                        void* outv, int n_nodes, int n_tiles)
{
    __shared__ float Wl[128 * 128];

    const int t = threadIdx.x;
    for (int idx = t; idx < (128 * 128) / 4; idx += 256) {
        float4 w = ((const float4*)W)[idx];
        const int j = idx >> 5;
        const int k = (idx & 31) << 2;
        const int ks = k ^ ((j & 7) << 2);
        *((float4*)&Wl[j * 128 + ks]) = w;
    }
    __syncthreads();

    const int j = t & 127;
    const int h = t >> 7;
    const float bj = b[j];
    const int swz = (j & 7) << 2;

    for (int tile = blockIdx.x; tile < n_tiles; tile += gridDim.x) {
        const int n0 = tile * 8 + h * 4;
        const int m0 = n0 + 0 < n_nodes ? n0 + 0 : n_nodes - 1;
        const int m1 = n0 + 1 < n_nodes ? n0 + 1 : n_nodes - 1;
        const int m2 = n0 + 2 < n_nodes ? n0 + 2 : n_nodes - 1;
        const int m3 = n0 + 3 < n_nodes ? n0 + 3 : n_nodes - 1;
        const float4* x0 = (const float4*)(in + (size_t)m0 * DIM);
        const float4* x1 = (const float4*)(in + (size_t)m1 * DIM);
        const float4* x2 = (const float4*)(in + (size_t)m2 * DIM);
        const float4* x3 = (const float4*)(in + (size_t)m3 * DIM);

        float acc0 = bj, acc1 = bj, acc2 = bj, acc3 = bj;

        #pragma unroll 8
        for (int kc = 0; kc < 32; ++kc) {
            const float4 w = *((const float4*)&Wl[j * 128 + ((kc << 2) ^ swz)]);
            const float4 a = x0[kc];
            const float4 c = x1[kc];
            const float4 d = x2[kc];
            const float4 e = x3[kc];
            acc0 += w.x * a.x + w.y * a.y + w.z * a.z + w.w * a.w;
            acc1 += w.x * c.x + w.y * c.y + w.z * c.z + w.w * c.w;
            acc2 += w.x * d.x + w.y * d.y + w.z * d.z + w.w * d.w;
            acc3 += w.x * e.x + w.y * e.y + w.z * e.z + w.w * e.w;
        }

        float r0 = fmaxf(acc0, 0.f);
        float r1 = fmaxf(acc1, 0.f);
        float r2 = fmaxf(acc2, 0.f);
        float r3 = fmaxf(acc3, 0.f);
        if (RESID) {
            r0 += xres[(size_t)m0 * DIM + j];
            r1 += xres[(size_t)m1 * DIM + j];
            r2 += xres[(size_t)m2 * DIM + j];
            r3 += xres[(size_t)m3 * DIM + j];
            __syncthreads();   // in-place: all reads of this tile done before writes
        }
        if constexpr (BF16OUT) {
            __hip_bfloat16* o = (__hip_bfloat16*)outv;
            if (n0 + 0 < n_nodes) o[(size_t)m0 * DIM + j] = __float2bfloat16(r0);
            if (n0 + 1 < n_nodes) o[(size_t)m1 * DIM + j] = __float2bfloat16(r1);
            if (n0 + 2 < n_nodes) o[(size_t)m2 * DIM + j] = __float2bfloat16(r2);
            if (n0 + 3 < n_nodes) o[(size_t)m3 * DIM + j] = __float2bfloat16(r3);
        } else {
            float* o = (float*)outv;
            if (n0 + 0 < n_nodes) o[(size_t)m0 * DIM + j] = r0;
            if (n0 + 1 < n_nodes) o[(size_t)m1 * DIM + j] = r1;
            if (n0 + 2 < n_nodes) o[(size_t)m2 * DIM + j] = r2;
            if (n0 + 3 < n_nodes) o[(size_t)m3 * DIM + j] = r3;
        }
    }
}

__global__ __launch_bounds__(256)
void count_kernel(const int* __restrict__ ei, int* __restrict__ counts, int n_edges)
{
    const int e = blockIdx.x * 256 + threadIdx.x;
    if (e < n_edges) atomicAdd(&counts[ei[n_edges + e]], 1);
}

// exclusive scan of up to 1024 elements per block (256 thr x 4); block total -> sums
__global__ __launch_bounds__(256)
void scan1024_kernel(const int* __restrict__ in, int* __restrict__ out,
                     int* __restrict__ sums, int n)
{
    __shared__ int s[256];
    const int t = threadIdx.x;
    const int base = blockIdx.x * 1024 + t * 4;
    const int v0 = base + 0 < n ? in[base + 0] : 0;
    const int v1 = base + 1 < n ? in[base + 1] : 0;
    const int v2 = base + 2 < n ? in[base + 2] : 0;
    const int v3 = base + 3 < n ? in[base + 3] : 0;
    s[t] = v0 + v1 + v2 + v3;
    __syncthreads();
    for (int off = 1; off < 256; off <<= 1) {
        const int add = t >= off ? s[t - off] : 0;
        __syncthreads();
        s[t] += add;
        __syncthreads();
    }
    if (t == 255) sums[blockIdx.x] = s[255];
    int run = t ? s[t - 1] : 0;
    if (base + 0 < n) out[base + 0] = run; run += v0;
    if (base + 1 < n) out[base + 1] = run; run += v1;
    if (base + 2 < n) out[base + 2] = run; run += v2;
    if (base + 3 < n) out[base + 3] = run;
}

__global__ __launch_bounds__(256)
void add_offsets_kernel(int* __restrict__ offsets, const int* __restrict__ boffs,
                        int n, int total)
{
    const int i = blockIdx.x * 256 + threadIdx.x;
    if (i < n) offsets[i] += boffs[i >> 10];
    if (i == 0) offsets[n] = total;
}

// cursor[] starts equal to counts[]; atomicSub hands out slots offsets[dst]..+count-1
__global__ __launch_bounds__(256)
void fill_kernel(const int* __restrict__ ei, const int* __restrict__ offsets,
                 int* __restrict__ cursor, int* __restrict__ edge_src, int n_edges)
{
    const int e = blockIdx.x * 256 + threadIdx.x;
    if (e >= n_edges) return;
    const int dst = ei[n_edges + e];
    const int c = atomicSub(&cursor[dst], 1);
    edge_src[offsets[dst] + c - 1] = ei[e];
}

// one wave per dst node: pull its incoming bf16 message rows, fp32-accumulate,
// write the agg row once. lane l owns elements 2l, 2l+1 (one uint = 2 bf16).
__global__ __launch_bounds__(256)
void gather_kernel(const __hip_bfloat16* __restrict__ msgv,
                   const int* __restrict__ offsets, const int* __restrict__ edge_src,
                   float* __restrict__ agg, int n_nodes)
{
    const uint* msg = (const uint*)msgv;
    const int lane = threadIdx.x & 63;
    const int wid = (blockIdx.x * 256 + threadIdx.x) >> 6;
    const int nw = (gridDim.x * 256) >> 6;
    for (int n = wid; n < n_nodes; n += nw) {
        const int s0 = offsets[n], s1 = offsets[n + 1];
        float a0 = 0.f, a1 = 0.f;
        for (int i = s0; i < s1; ++i) {
            const int src = edge_src[i];
            const uint m = msg[(size_t)src * 64 + lane];
            a0 += __uint_as_float(m << 16);
            a1 += __uint_as_float(m & 0xffff0000u);
        }
        ((float2*)(agg + (size_t)n * DIM))[lane] = make_float2(a0, a1);
    }
}

extern "C" void kernel_launch(void* const* d_in, const int* in_sizes, int n_in,
                              void* d_out, int out_size, void* d_ws, size_t ws_size,
                              hipStream_t stream)
{
    const float* x  = (const float*)d_in[0];
    const int*   ei = (const int*)d_in[1];
    const float* Wm = (const float*)d_in[2];
    const float* bm = (const float*)d_in[3];
    const float* Wu = (const float*)d_in[4];
    const float* bu = (const float*)d_in[5];

    const int N = in_sizes[0] / DIM;   // 100000
    const int E = in_sizes[1] / 2;     // 1600000

    // workspace layout (~32.8 MB; round-1 proved ws >= 51.2 MB)
    char* ws = (char*)d_ws;
    __hip_bfloat16* msg = (__hip_bfloat16*)ws;                 // N*128 bf16 = 25.6 MB
    size_t o = (size_t)N * DIM * sizeof(__hip_bfloat16);
    int* counts  = (int*)(ws + o); o += (size_t)N * 4;         // 0.4 MB
    int* offsets = (int*)(ws + o); o += ((size_t)N + 1) * 4;   // 0.4 MB
    o = (o + 255) & ~(size_t)255;
    int* bsums    = (int*)(ws + o); o += 1024;
    int* boffs    = (int*)(ws + o); o += 1024;
    int* bscratch = (int*)(ws + o); o += 1024;
    int* edge_src = (int*)(ws + o);                            // E ints = 6.4 MB

    float* out = (float*)d_out;
    float* agg = out;                  // agg lives in d_out; update runs in-place

    const int n_tiles = (N + 7) / 8;
    const int NBLK = (N + 1023) / 1024;

    // 1) messages (bf16) = relu(x @ Wm^T + bm) -> ws
    linear_relu_kernel<false, true><<<512, 256, 0, stream>>>(x, Wm, bm, nullptr, msg, N, n_tiles);

    // 2) CSR by dst
    hipMemsetAsync(counts, 0, (size_t)N * 4, stream);
    count_kernel<<<(E + 255) / 256, 256, 0, stream>>>(ei, counts, E);
    scan1024_kernel<<<NBLK, 256, 0, stream>>>(counts, offsets, bsums, N);
    scan1024_kernel<<<1, 256, 0, stream>>>(bsums, boffs, bscratch, NBLK);
    add_offsets_kernel<<<(N + 255) / 256, 256, 0, stream>>>(offsets, boffs, N, E);
    fill_kernel<<<(E + 255) / 256, 256, 0, stream>>>(ei, offsets, counts, edge_src, E);

    // 3) agg[n] = sum over incoming edges of msg[src]  (pull, no atomics) -> d_out
    gather_kernel<<<2048, 256, 0, stream>>>(msg, offsets, edge_src, agg, N);

    // 4) out = relu(agg @ Wu^T + bu) + x   (in-place on d_out)
    linear_relu_kernel<true, false><<<512, 256, 0, stream>>>(agg, Wu, bu, x, out, N, n_tiles);
}

// Round 3
// 295.851 us; speedup vs baseline: 10.6375x; 2.5874x over previous
//
#include <hip/hip_runtime.h>
#include <hip/hip_bf16.h>

#define DIM 128

typedef __attribute__((ext_vector_type(8))) short bf16x8;
typedef __attribute__((ext_vector_type(4))) float f32x4;

__device__ inline ushort f2bf(float f) {
    uint u = __float_as_uint(f);
    u += 0x7fffu + ((u >> 16) & 1u);   // RNE (inputs are finite, no NaN care)
    return (ushort)(u >> 16);
}
__device__ inline uint pack2(float lo, float hi) {
    return (uint)f2bf(lo) | ((uint)f2bf(hi) << 16);
}

// out[n][j] = relu(b[j] + sum_k in[n][k] * W[j][k])  (+ xres[n][j] if RESID)
// MFMA 16x16x32 bf16. One wave owns one 16-row tile (in-place safe: reads its
// rows fully into registers before writing them). k-mapping for A and B frags
// is the SAME assumed bijection k = (lane>>4)*32 + ks*8 + r -> result is
// correct regardless of the true internal operand k-map (dot products are
// invariant under identical permutation of both operands). C layout is the
// m89-verified one: col = lane&15, row = (lane>>4)*4 + reg.
// W staged in LDS as bf16, 16B chunks XOR-swizzled: chunk c of row j at
// position c ^ (j&15)  -> column reads spread across all 16 chunk slots.
template<bool RESID, bool BF16OUT>
__global__ __launch_bounds__(256, 2)
void linear_mfma_kernel(const float* in, const float* __restrict__ W,
                        const float* __restrict__ b, const float* __restrict__ xres,
                        void* outv, int n_tiles)
{
    __shared__ uint4 Wl[128 * 16];   // 32 KB

    const int t = threadIdx.x;
    for (int q = t; q < 2048; q += 256) {           // 2048 chunks of 8 floats
        const int j = q >> 4, c = q & 15;
        const float4 lo = ((const float4*)(W + j * 128 + c * 8))[0];
        const float4 hi = ((const float4*)(W + j * 128 + c * 8))[1];
        uint4 pk;
        pk.x = pack2(lo.x, lo.y); pk.y = pack2(lo.z, lo.w);
        pk.z = pack2(hi.x, hi.y); pk.w = pack2(hi.z, hi.w);
        Wl[j * 16 + (c ^ (j & 15))] = pk;
    }
    __syncthreads();

    const int lane = t & 63;
    const int lo4 = lane & 15;   // A row-in-tile / B,C col-in-tile
    const int g   = lane >> 4;   // k-group

    float bias[8];
    #pragma unroll
    for (int ct = 0; ct < 8; ++ct) bias[ct] = b[ct * 16 + lo4];

    const int wid = (blockIdx.x * 256 + t) >> 6;
    const int nw  = (gridDim.x * 256) >> 6;

    for (int tile = wid; tile < n_tiles; tile += nw) {
        const int arow = tile * 16 + lo4;
        const float4* ap = (const float4*)(in + (size_t)arow * DIM + g * 32);
        float4 v[8];
        #pragma unroll
        for (int i = 0; i < 8; ++i) v[i] = ap[i];   // 32 contiguous floats/lane

        bf16x8 afrag[4];
        #pragma unroll
        for (int ks = 0; ks < 4; ++ks) {
            union { bf16x8 v8; uint u[4]; } a;
            a.u[0] = pack2(v[2*ks].x,   v[2*ks].y);
            a.u[1] = pack2(v[2*ks].z,   v[2*ks].w);
            a.u[2] = pack2(v[2*ks+1].x, v[2*ks+1].y);
            a.u[3] = pack2(v[2*ks+1].z, v[2*ks+1].w);
            afrag[ks] = a.v8;
        }

        f32x4 acc[8];
        #pragma unroll
        for (int ct = 0; ct < 8; ++ct)
            acc[ct] = (f32x4){bias[ct], bias[ct], bias[ct], bias[ct]};

        #pragma unroll
        for (int ks = 0; ks < 4; ++ks) {
            #pragma unroll
            for (int ct = 0; ct < 8; ++ct) {
                const int jrow = ct * 16 + lo4;
                const bf16x8 bfrag = *((const bf16x8*)&Wl[jrow * 16 + ((g * 4 + ks) ^ lo4)]);
                acc[ct] = __builtin_amdgcn_mfma_f32_16x16x32_bf16(afrag[ks], bfrag, acc[ct], 0, 0, 0);
            }
        }

        #pragma unroll
        for (int ct = 0; ct < 8; ++ct) {
            #pragma unroll
            for (int r = 0; r < 4; ++r) {
                const int orow = tile * 16 + g * 4 + r;
                const int ocol = ct * 16 + lo4;
                float val = fmaxf(acc[ct][r], 0.f);
                if constexpr (RESID) val += xres[(size_t)orow * DIM + ocol];
                if constexpr (BF16OUT)
                    ((ushort*)outv)[(size_t)orow * DIM + ocol] = f2bf(val);
                else
                    ((float*)outv)[(size_t)orow * DIM + ocol] = val;
            }
        }
    }
}

__global__ __launch_bounds__(256)
void count_kernel(const int* __restrict__ ei, int* __restrict__ counts, int n_edges)
{
    const int e = blockIdx.x * 256 + threadIdx.x;
    if (e < n_edges) atomicAdd(&counts[ei[n_edges + e]], 1);
}

__global__ __launch_bounds__(256)
void scan1024_kernel(const int* __restrict__ in, int* __restrict__ out,
                     int* __restrict__ sums, int n)
{
    __shared__ int s[256];
    const int t = threadIdx.x;
    const int base = blockIdx.x * 1024 + t * 4;
    const int v0 = base + 0 < n ? in[base + 0] : 0;
    const int v1 = base + 1 < n ? in[base + 1] : 0;
    const int v2 = base + 2 < n ? in[base + 2] : 0;
    const int v3 = base + 3 < n ? in[base + 3] : 0;
    s[t] = v0 + v1 + v2 + v3;
    __syncthreads();
    for (int off = 1; off < 256; off <<= 1) {
        const int add = t >= off ? s[t - off] : 0;
        __syncthreads();
        s[t] += add;
        __syncthreads();
    }
    if (t == 255) sums[blockIdx.x] = s[255];
    int run = t ? s[t - 1] : 0;
    if (base + 0 < n) out[base + 0] = run; run += v0;
    if (base + 1 < n) out[base + 1] = run; run += v1;
    if (base + 2 < n) out[base + 2] = run; run += v2;
    if (base + 3 < n) out[base + 3] = run;
}

__global__ __launch_bounds__(256)
void add_offsets_kernel(int* __restrict__ offsets, const int* __restrict__ boffs,
                        int n, int total)
{
    const int i = blockIdx.x * 256 + threadIdx.x;
    if (i < n) offsets[i] += boffs[i >> 10];
    if (i == 0) offsets[n] = total;
}

__global__ __launch_bounds__(256)
void fill_kernel(const int* __restrict__ ei, const int* __restrict__ offsets,
                 int* __restrict__ cursor, int* __restrict__ edge_src, int n_edges)
{
    const int e = blockIdx.x * 256 + threadIdx.x;
    if (e >= n_edges) return;
    const int dst = ei[n_edges + e];
    const int c = atomicSub(&cursor[dst], 1);
    edge_src[offsets[dst] + c - 1] = ei[e];
}

// one wave per dst node; 4 edges in flight per iteration (MLP x4)
__global__ __launch_bounds__(256)
void gather_kernel(const uint* __restrict__ msg, const int* __restrict__ offsets,
                   const int* __restrict__ edge_src, float* __restrict__ agg, int n_nodes)
{
    const int lane = threadIdx.x & 63;
    const int wid = (blockIdx.x * 256 + threadIdx.x) >> 6;
    const int nw = (gridDim.x * 256) >> 6;
    for (int n = wid; n < n_nodes; n += nw) {
        const int s0 = offsets[n], s1 = offsets[n + 1];
        float a0 = 0.f, a1 = 0.f;
        int i = s0;
        for (; i + 4 <= s1; i += 4) {
            const int sA = edge_src[i + 0], sB = edge_src[i + 1];
            const int sC = edge_src[i + 2], sD = edge_src[i + 3];
            const uint mA = msg[(size_t)sA * 64 + lane];
            const uint mB = msg[(size_t)sB * 64 + lane];
            const uint mC = msg[(size_t)sC * 64 + lane];
            const uint mD = msg[(size_t)sD * 64 + lane];
            a0 += __uint_as_float(mA << 16) + __uint_as_float(mB << 16)
                + __uint_as_float(mC << 16) + __uint_as_float(mD << 16);
            a1 += __uint_as_float(mA & 0xffff0000u) + __uint_as_float(mB & 0xffff0000u)
                + __uint_as_float(mC & 0xffff0000u) + __uint_as_float(mD & 0xffff0000u);
        }
        for (; i < s1; ++i) {
            const uint m = msg[(size_t)edge_src[i] * 64 + lane];
            a0 += __uint_as_float(m << 16);
            a1 += __uint_as_float(m & 0xffff0000u);
        }
        ((float2*)(agg + (size_t)n * DIM))[lane] = make_float2(a0, a1);
    }
}

extern "C" void kernel_launch(void* const* d_in, const int* in_sizes, int n_in,
                              void* d_out, int out_size, void* d_ws, size_t ws_size,
                              hipStream_t stream)
{
    const float* x  = (const float*)d_in[0];
    const int*   ei = (const int*)d_in[1];
    const float* Wm = (const float*)d_in[2];
    const float* bm = (const float*)d_in[3];
    const float* Wu = (const float*)d_in[4];
    const float* bu = (const float*)d_in[5];

    const int N = in_sizes[0] / DIM;   // 100000 (divisible by 16)
    const int E = in_sizes[1] / 2;     // 1600000

    // workspace layout (~32.8 MB; ws >= 51.2 MB proven in round 1)
    char* ws = (char*)d_ws;
    ushort* msg = (ushort*)ws;                                 // N*128 bf16
    size_t o = (size_t)N * DIM * sizeof(ushort);
    int* counts  = (int*)(ws + o); o += (size_t)N * 4;
    int* offsets = (int*)(ws + o); o += ((size_t)N + 1) * 4;
    o = (o + 255) & ~(size_t)255;
    int* bsums    = (int*)(ws + o); o += 1024;
    int* boffs    = (int*)(ws + o); o += 1024;
    int* bscratch = (int*)(ws + o); o += 1024;
    int* edge_src = (int*)(ws + o);                            // E ints

    float* out = (float*)d_out;
    float* agg = out;                  // agg lives in d_out; update is in-place

    const int n_tiles = N / 16;        // 6250
    const int NBLK = (N + 1023) / 1024;

    // 1) messages (bf16) = relu(x @ Wm^T + bm) -> ws
    linear_mfma_kernel<false, true><<<512, 256, 0, stream>>>(x, Wm, bm, nullptr, msg, n_tiles);

    // 2) CSR by dst
    hipMemsetAsync(counts, 0, (size_t)N * 4, stream);
    count_kernel<<<(E + 255) / 256, 256, 0, stream>>>(ei, counts, E);
    scan1024_kernel<<<NBLK, 256, 0, stream>>>(counts, offsets, bsums, N);
    scan1024_kernel<<<1, 256, 0, stream>>>(bsums, boffs, bscratch, NBLK);
    add_offsets_kernel<<<(N + 255) / 256, 256, 0, stream>>>(offsets, boffs, N, E);
    fill_kernel<<<(E + 255) / 256, 256, 0, stream>>>(ei, offsets, counts, edge_src, E);

    // 3) agg[n] = sum_{incoming} msg[src]  (pull, no atomics) -> d_out
    gather_kernel<<<2048, 256, 0, stream>>>((const uint*)msg, offsets, edge_src, agg, N);

    // 4) out = relu(agg @ Wu^T + bu) + x   (in-place on d_out)
    linear_mfma_kernel<true, false><<<512, 256, 0, stream>>>(agg, Wu, bu, x, out, n_tiles);
}